// Round 1
// baseline (967.918 us; speedup 1.0000x reference)
//
#include <hip/hip_runtime.h>
#include <math.h>

// ---------------- graph preprocessing ----------------

__global__ void k_init(int* __restrict__ ecnt, int* __restrict__ cursor, int N) {
    int i = blockIdx.x * 256 + threadIdx.x;
    if (i < N) { ecnt[i] = 0; cursor[i] = 0; }
}

__global__ void k_edge_count(const int* __restrict__ dst, int* __restrict__ ecnt, int E) {
    int i = blockIdx.x * 256 + threadIdx.x;
    if (i < E) atomicAdd(&ecnt[dst[i]], 1);
}

__global__ void k_scanA(const int* __restrict__ ecnt, int* __restrict__ bsum, int N) {
    int t = threadIdx.x;
    int base = blockIdx.x * 1024;
    int s = 0;
#pragma unroll
    for (int j = 0; j < 4; ++j) {
        int i = base + j * 256 + t;
        if (i < N) s += ecnt[i];
    }
#pragma unroll
    for (int off = 32; off > 0; off >>= 1) s += __shfl_down(s, off, 64);
    __shared__ int wsum[4];
    if ((t & 63) == 0) wsum[t >> 6] = s;
    __syncthreads();
    if (t == 0) bsum[blockIdx.x] = wsum[0] + wsum[1] + wsum[2] + wsum[3];
}

// single-block exclusive scan of NB (<=256) block sums
__global__ void k_scanB(const int* __restrict__ bsum, int* __restrict__ boff, int NB) {
    __shared__ int sh[256];
    int t = threadIdx.x;
    int v = (t < NB) ? bsum[t] : 0;
    sh[t] = v;
    __syncthreads();
    for (int off = 1; off < 256; off <<= 1) {
        int u = (t >= off) ? sh[t - off] : 0;
        __syncthreads();
        sh[t] += u;
        __syncthreads();
    }
    if (t < NB) boff[t] = sh[t] - v;  // exclusive
}

__global__ void k_scanC(const int* __restrict__ ecnt, const int* __restrict__ boff,
                        int* __restrict__ rowstart, float* __restrict__ dinv, int N) {
    int t = threadIdx.x;
    int base = blockIdx.x * 1024 + t * 4;
    int e[4];
    int s = 0;
#pragma unroll
    for (int j = 0; j < 4; ++j) {
        int i = base + j;
        e[j] = (i < N) ? ecnt[i] : 0;
        s += e[j];
    }
    __shared__ int sh[256];
    sh[t] = s;
    __syncthreads();
    for (int off = 1; off < 256; off <<= 1) {
        int u = (t >= off) ? sh[t - off] : 0;
        __syncthreads();
        sh[t] += u;
        __syncthreads();
    }
    int off0 = boff[blockIdx.x] + sh[t] - s;  // exclusive prefix for this thread's 4 elems
    int run = 0;
#pragma unroll
    for (int j = 0; j < 4; ++j) {
        int i = base + j;
        if (i < N) {
            rowstart[i] = off0 + run;
            dinv[i] = rsqrtf((float)(e[j] + 1));  // +1 self loop
        }
        run += e[j];
    }
}

__global__ void k_tail(int* __restrict__ rowstart, int N, int E) {
    rowstart[N] = E;
}

__global__ void k_scatter(const int* __restrict__ src, const int* __restrict__ dst,
                          const int* __restrict__ rowstart, int* __restrict__ cursor,
                          int* __restrict__ ssrc, int E) {
    int i = blockIdx.x * 256 + threadIdx.x;
    if (i < E) {
        int v = dst[i];
        int p = rowstart[v] + atomicAdd(&cursor[v], 1);
        ssrc[p] = src[i];
    }
}

__global__ void k_gstarts(const int* __restrict__ batch, int* __restrict__ gstart, int N, int G) {
    int i = blockIdx.x * 256 + threadIdx.x;
    if (i >= N) return;
    int bi = batch[i];
    int bp = (i == 0) ? -1 : batch[i - 1];
    for (int g = bp + 1; g <= bi; ++g) gstart[g] = i;
    if (i == N - 1) {
        for (int g = bi + 1; g <= G; ++g) gstart[g] = N;
    }
}

// ---------------- GEMM: C[r, 0..255] = dinv[r] * (A[r,:] @ W) ----------------
// BM=64, BN=64, BK=32, 256 threads, 4x4 per thread. M fixed = 256, K % 32 == 0.

__global__ __launch_bounds__(256) void k_gemm_scale(
    const float* __restrict__ A, const float* __restrict__ W,
    const float* __restrict__ dinv, float* __restrict__ C, int Nrows, int K) {
    __shared__ float As[32][64];  // [k][row]
    __shared__ float Ws[32][64];  // [k][col]
    int row0 = blockIdx.x * 64, col0 = blockIdx.y * 64;
    int tid = threadIdx.x;
    int tx = tid & 15, ty = tid >> 4;
    float acc[4][4] = {};
    for (int k0 = 0; k0 < K; k0 += 32) {
        // A tile: 64 rows x 32 cols = 512 float4, 2 per thread
#pragma unroll
        for (int i = 0; i < 2; ++i) {
            int idx = tid * 2 + i;
            int r = idx >> 3;
            int c4 = (idx & 7) * 4;
            int gr = row0 + r;
            float4 v = make_float4(0.f, 0.f, 0.f, 0.f);
            if (gr < Nrows) v = *(const float4*)&A[(size_t)gr * K + k0 + c4];
            As[c4 + 0][r] = v.x;
            As[c4 + 1][r] = v.y;
            As[c4 + 2][r] = v.z;
            As[c4 + 3][r] = v.w;
        }
        // W tile: 32 rows x 64 cols = 512 float4, 2 per thread
#pragma unroll
        for (int i = 0; i < 2; ++i) {
            int idx = tid * 2 + i;
            int kr = idx >> 4;
            int c4 = (idx & 15) * 4;
            *(float4*)&Ws[kr][c4] = *(const float4*)&W[(size_t)(k0 + kr) * 256 + col0 + c4];
        }
        __syncthreads();
#pragma unroll
        for (int kk = 0; kk < 32; ++kk) {
            float4 a4 = *(const float4*)&As[kk][ty * 4];
            float4 b4 = *(const float4*)&Ws[kk][tx * 4];
            float av[4] = {a4.x, a4.y, a4.z, a4.w};
            float bv[4] = {b4.x, b4.y, b4.z, b4.w};
#pragma unroll
            for (int i = 0; i < 4; ++i)
#pragma unroll
                for (int j = 0; j < 4; ++j) acc[i][j] = fmaf(av[i], bv[j], acc[i][j]);
        }
        __syncthreads();
    }
#pragma unroll
    for (int i = 0; i < 4; ++i) {
        int r = row0 + ty * 4 + i;
        if (r < Nrows) {
            float sc = dinv[r];
            float4 o = make_float4(acc[i][0] * sc, acc[i][1] * sc, acc[i][2] * sc, acc[i][3] * sc);
            *(float4*)&C[(size_t)r * 256 + col0 + tx * 4] = o;
        }
    }
}

// ---------------- aggregation: out[v] = relu(dinv[v] * (hs[v] + sum_{u->v} hs[u]) + b) --------
// one wave (64 lanes) per node, float4 per lane covers 256 dims

__global__ __launch_bounds__(256) void k_aggregate(
    const float* __restrict__ hs, const int* __restrict__ rowstart,
    const int* __restrict__ ssrc, const float* __restrict__ dinv,
    const float* __restrict__ bias, float* __restrict__ out, int N) {
    int w = threadIdx.x >> 6;
    int l = threadIdx.x & 63;
    int v = blockIdx.x * 4 + w;
    if (v >= N) return;
    float4 acc = *(const float4*)(hs + (size_t)v * 256 + l * 4);  // self loop
    int s0 = rowstart[v], s1 = rowstart[v + 1];
    for (int e = s0; e < s1; ++e) {
        int u = ssrc[e];
        float4 m = *(const float4*)(hs + (size_t)u * 256 + l * 4);
        acc.x += m.x; acc.y += m.y; acc.z += m.z; acc.w += m.w;
    }
    float d = dinv[v];
    float4 b = *(const float4*)(bias + l * 4);
    float4 o;
    o.x = fmaxf(fmaf(acc.x, d, b.x), 0.f);
    o.y = fmaxf(fmaf(acc.y, d, b.y), 0.f);
    o.z = fmaxf(fmaf(acc.z, d, b.z), 0.f);
    o.w = fmaxf(fmaf(acc.w, d, b.w), 0.f);
    *(float4*)(out + (size_t)v * 256 + l * 4) = o;
}

// ---------------- pooled mean + linear head ----------------

__global__ __launch_bounds__(256) void k_pool_head(
    const float* __restrict__ h2, const int* __restrict__ gstart,
    const float* __restrict__ Wl, const float* __restrict__ bl,
    float* __restrict__ out, int G) {
    int g = blockIdx.x;
    int t = threadIdx.x;
    int i0 = gstart[g], i1 = gstart[g + 1];
    float s = 0.f;
    for (int i = i0; i < i1; ++i) s += h2[(size_t)i * 256 + t];
    float cnt = (float)(i1 - i0);
    float pooled = s / fmaxf(cnt, 1.f);
    float v = pooled * Wl[t];
#pragma unroll
    for (int off = 32; off > 0; off >>= 1) v += __shfl_down(v, off, 64);
    __shared__ float red[4];
    if ((t & 63) == 0) red[t >> 6] = v;
    __syncthreads();
    if (t == 0) out[g] = red[0] + red[1] + red[2] + red[3] + bl[0];
}

// ---------------- launch ----------------

extern "C" void kernel_launch(void* const* d_in, const int* in_sizes, int n_in,
                              void* d_out, int out_size, void* d_ws, size_t ws_size,
                              hipStream_t stream) {
    const float* x  = (const float*)d_in[0];
    const int* ei   = (const int*)d_in[1];
    const int* batch= (const int*)d_in[2];
    const float* W1 = (const float*)d_in[3];
    const float* b1 = (const float*)d_in[4];
    const float* W2 = (const float*)d_in[5];
    const float* b2 = (const float*)d_in[6];
    const float* Wl = (const float*)d_in[7];
    const float* bl = (const float*)d_in[8];
    float* out = (float*)d_out;

    const int N = in_sizes[2];          // nodes (batch array length)
    const int E = in_sizes[1] / 2;      // edges
    const int G = out_size;             // graphs
    const int DIN = in_sizes[0] / N;    // 128
    const int DH = 256;

    char* wsp = (char*)d_ws;
    size_t off = 0;
    auto carve = [&](size_t bytes) -> void* {
        void* p = wsp + off;
        off = (off + bytes + 255) & ~(size_t)255;
        return p;
    };
    float* hs      = (float*)carve((size_t)N * DH * 4);
    float* hb      = (float*)carve((size_t)N * DH * 4);
    float* dinv    = (float*)carve((size_t)N * 4);
    int* ecnt      = (int*)carve((size_t)N * 4);
    int* rowstart  = (int*)carve((size_t)(N + 1) * 4);
    int* cursor    = (int*)carve((size_t)N * 4);
    int* ssrc      = (int*)carve((size_t)E * 4);
    const int NB = (N + 1023) / 1024;
    int* bsum      = (int*)carve((size_t)NB * 4);
    int* boff      = (int*)carve((size_t)NB * 4);
    int* gstart    = (int*)carve((size_t)(G + 1) * 4);
    (void)ws_size;

    const int* esrc = ei;
    const int* edst = ei + E;

    int nb256 = (N + 255) / 256;
    int eb256 = (E + 255) / 256;

    hipLaunchKernelGGL(k_init, dim3(nb256), dim3(256), 0, stream, ecnt, cursor, N);
    hipLaunchKernelGGL(k_edge_count, dim3(eb256), dim3(256), 0, stream, edst, ecnt, E);
    hipLaunchKernelGGL(k_scanA, dim3(NB), dim3(256), 0, stream, ecnt, bsum, N);
    hipLaunchKernelGGL(k_scanB, dim3(1), dim3(256), 0, stream, bsum, boff, NB);
    hipLaunchKernelGGL(k_scanC, dim3(NB), dim3(256), 0, stream, ecnt, boff, rowstart, dinv, N);
    hipLaunchKernelGGL(k_tail, dim3(1), dim3(1), 0, stream, rowstart, N, E);
    hipLaunchKernelGGL(k_scatter, dim3(eb256), dim3(256), 0, stream, esrc, edst, rowstart, cursor, ssrc, E);
    hipLaunchKernelGGL(k_gstarts, dim3(nb256), dim3(256), 0, stream, batch, gstart, N, G);

    // layer 1: hs = dinv * (x @ W1); hb = relu(dinv * agg(hs) + b1)
    hipLaunchKernelGGL(k_gemm_scale, dim3((N + 63) / 64, 4), dim3(256), 0, stream,
                       x, W1, dinv, hs, N, DIN);
    hipLaunchKernelGGL(k_aggregate, dim3((N + 3) / 4), dim3(256), 0, stream,
                       hs, rowstart, ssrc, dinv, b1, hb, N);
    // layer 2
    hipLaunchKernelGGL(k_gemm_scale, dim3((N + 63) / 64, 4), dim3(256), 0, stream,
                       hb, W2, dinv, hs, N, DH);
    hipLaunchKernelGGL(k_aggregate, dim3((N + 3) / 4), dim3(256), 0, stream,
                       hs, rowstart, ssrc, dinv, b2, hb, N);
    // pool + head
    hipLaunchKernelGGL(k_pool_head, dim3(G), dim3(256), 0, stream, hb, gstart, Wl, bl, out, G);
}

// Round 2
// 855.691 us; speedup vs baseline: 1.1312x; 1.1312x over previous
//
#include <hip/hip_runtime.h>
#include <math.h>

// ---------------- graph preprocessing ----------------

__global__ void k_init(int* __restrict__ ecnt, int* __restrict__ cursor, int N) {
    int i = blockIdx.x * 256 + threadIdx.x;
    if (i < N) { ecnt[i] = 0; cursor[i] = 0; }
}

__global__ void k_edge_count(const int* __restrict__ dst, int* __restrict__ ecnt, int E) {
    int i = blockIdx.x * 256 + threadIdx.x;
    if (i < E) atomicAdd(&ecnt[dst[i]], 1);
}

__global__ void k_scanA(const int* __restrict__ ecnt, int* __restrict__ bsum, int N) {
    int t = threadIdx.x;
    int base = blockIdx.x * 1024;
    int s = 0;
#pragma unroll
    for (int j = 0; j < 4; ++j) {
        int i = base + j * 256 + t;
        if (i < N) s += ecnt[i];
    }
#pragma unroll
    for (int off = 32; off > 0; off >>= 1) s += __shfl_down(s, off, 64);
    __shared__ int wsum[4];
    if ((t & 63) == 0) wsum[t >> 6] = s;
    __syncthreads();
    if (t == 0) bsum[blockIdx.x] = wsum[0] + wsum[1] + wsum[2] + wsum[3];
}

__global__ void k_scanB(const int* __restrict__ bsum, int* __restrict__ boff, int NB) {
    __shared__ int sh[256];
    int t = threadIdx.x;
    int v = (t < NB) ? bsum[t] : 0;
    sh[t] = v;
    __syncthreads();
    for (int off = 1; off < 256; off <<= 1) {
        int u = (t >= off) ? sh[t - off] : 0;
        __syncthreads();
        sh[t] += u;
        __syncthreads();
    }
    if (t < NB) boff[t] = sh[t] - v;  // exclusive
}

__global__ void k_scanC(const int* __restrict__ ecnt, const int* __restrict__ boff,
                        int* __restrict__ rowstart, float* __restrict__ dinv, int N) {
    int t = threadIdx.x;
    int base = blockIdx.x * 1024 + t * 4;
    int e[4];
    int s = 0;
#pragma unroll
    for (int j = 0; j < 4; ++j) {
        int i = base + j;
        e[j] = (i < N) ? ecnt[i] : 0;
        s += e[j];
    }
    __shared__ int sh[256];
    sh[t] = s;
    __syncthreads();
    for (int off = 1; off < 256; off <<= 1) {
        int u = (t >= off) ? sh[t - off] : 0;
        __syncthreads();
        sh[t] += u;
        __syncthreads();
    }
    int off0 = boff[blockIdx.x] + sh[t] - s;
    int run = 0;
#pragma unroll
    for (int j = 0; j < 4; ++j) {
        int i = base + j;
        if (i < N) {
            rowstart[i] = off0 + run;
            dinv[i] = rsqrtf((float)(e[j] + 1));  // +1 self loop
        }
        run += e[j];
    }
}

__global__ void k_tail(int* __restrict__ rowstart, int N, int E) {
    rowstart[N] = E;
}

__global__ void k_scatter(const int* __restrict__ src, const int* __restrict__ dst,
                          const int* __restrict__ rowstart, int* __restrict__ cursor,
                          int* __restrict__ ssrc, int E) {
    int i = blockIdx.x * 256 + threadIdx.x;
    if (i < E) {
        int v = dst[i];
        int p = rowstart[v] + atomicAdd(&cursor[v], 1);
        ssrc[p] = src[i];
    }
}

__global__ void k_gstarts(const int* __restrict__ batch, int* __restrict__ gstart, int N, int G) {
    int i = blockIdx.x * 256 + threadIdx.x;
    if (i >= N) return;
    int bi = batch[i];
    int bp = (i == 0) ? -1 : batch[i - 1];
    for (int g = bp + 1; g <= bi; ++g) gstart[g] = i;
    if (i == N - 1) {
        for (int g = bi + 1; g <= G; ++g) gstart[g] = N;
    }
}

// ---------------- layer-1 input aggregation: xa[v] = dinv[v]*(dinv[v]*x[v] + sum dinv[u]*x[u]) ----
// half-wave (32 lanes) per node, float4/lane covers 128 dims

__global__ __launch_bounds__(256) void k_agg_in(
    const float* __restrict__ x, const int* __restrict__ rowstart,
    const int* __restrict__ ssrc, const float* __restrict__ dinv,
    float* __restrict__ xa, int N) {
    int half = threadIdx.x >> 5;
    int l = threadIdx.x & 31;
    int v = blockIdx.x * 8 + half;
    if (v >= N) return;
    float dv = dinv[v];
    float4 s = *(const float4*)(x + (size_t)v * 128 + l * 4);
    float4 acc = make_float4(s.x * dv, s.y * dv, s.z * dv, s.w * dv);
    int e = rowstart[v], e1 = rowstart[v + 1];
    for (; e + 4 <= e1; e += 4) {
        int u0 = ssrc[e], u1 = ssrc[e + 1], u2 = ssrc[e + 2], u3 = ssrc[e + 3];
        float d0 = dinv[u0], d1 = dinv[u1], d2 = dinv[u2], d3 = dinv[u3];
        float4 m0 = *(const float4*)(x + (size_t)u0 * 128 + l * 4);
        float4 m1 = *(const float4*)(x + (size_t)u1 * 128 + l * 4);
        float4 m2 = *(const float4*)(x + (size_t)u2 * 128 + l * 4);
        float4 m3 = *(const float4*)(x + (size_t)u3 * 128 + l * 4);
        acc.x = fmaf(m0.x, d0, acc.x); acc.y = fmaf(m0.y, d0, acc.y);
        acc.z = fmaf(m0.z, d0, acc.z); acc.w = fmaf(m0.w, d0, acc.w);
        acc.x = fmaf(m1.x, d1, acc.x); acc.y = fmaf(m1.y, d1, acc.y);
        acc.z = fmaf(m1.z, d1, acc.z); acc.w = fmaf(m1.w, d1, acc.w);
        acc.x = fmaf(m2.x, d2, acc.x); acc.y = fmaf(m2.y, d2, acc.y);
        acc.z = fmaf(m2.z, d2, acc.z); acc.w = fmaf(m2.w, d2, acc.w);
        acc.x = fmaf(m3.x, d3, acc.x); acc.y = fmaf(m3.y, d3, acc.y);
        acc.z = fmaf(m3.z, d3, acc.z); acc.w = fmaf(m3.w, d3, acc.w);
    }
    for (; e < e1; ++e) {
        int u = ssrc[e];
        float d = dinv[u];
        float4 m = *(const float4*)(x + (size_t)u * 128 + l * 4);
        acc.x = fmaf(m.x, d, acc.x); acc.y = fmaf(m.y, d, acc.y);
        acc.z = fmaf(m.z, d, acc.z); acc.w = fmaf(m.w, d, acc.w);
    }
    float4 o = make_float4(acc.x * dv, acc.y * dv, acc.z * dv, acc.w * dv);
    *(float4*)(xa + (size_t)v * 128 + l * 4) = o;
}

// ---------------- layer-2 aggregation: out[v] = relu(dinv[v]*(hs[v] + sum hs[u]) + b) ----------
// one wave per node, float4/lane covers 256 dims, unroll 4

__global__ __launch_bounds__(256) void k_aggregate(
    const float* __restrict__ hs, const int* __restrict__ rowstart,
    const int* __restrict__ ssrc, const float* __restrict__ dinv,
    const float* __restrict__ bias, float* __restrict__ out, int N) {
    int w = threadIdx.x >> 6;
    int l = threadIdx.x & 63;
    int v = blockIdx.x * 4 + w;
    if (v >= N) return;
    float4 acc = *(const float4*)(hs + (size_t)v * 256 + l * 4);  // self loop
    int e = rowstart[v], e1 = rowstart[v + 1];
    for (; e + 4 <= e1; e += 4) {
        int u0 = ssrc[e], u1 = ssrc[e + 1], u2 = ssrc[e + 2], u3 = ssrc[e + 3];
        float4 m0 = *(const float4*)(hs + (size_t)u0 * 256 + l * 4);
        float4 m1 = *(const float4*)(hs + (size_t)u1 * 256 + l * 4);
        float4 m2 = *(const float4*)(hs + (size_t)u2 * 256 + l * 4);
        float4 m3 = *(const float4*)(hs + (size_t)u3 * 256 + l * 4);
        acc.x += m0.x + m1.x + m2.x + m3.x;
        acc.y += m0.y + m1.y + m2.y + m3.y;
        acc.z += m0.z + m1.z + m2.z + m3.z;
        acc.w += m0.w + m1.w + m2.w + m3.w;
    }
    for (; e < e1; ++e) {
        int u = ssrc[e];
        float4 m = *(const float4*)(hs + (size_t)u * 256 + l * 4);
        acc.x += m.x; acc.y += m.y; acc.z += m.z; acc.w += m.w;
    }
    float d = dinv[v];
    float4 b = *(const float4*)(bias + l * 4);
    float4 o;
    o.x = fmaxf(fmaf(acc.x, d, b.x), 0.f);
    o.y = fmaxf(fmaf(acc.y, d, b.y), 0.f);
    o.z = fmaxf(fmaf(acc.z, d, b.z), 0.f);
    o.w = fmaxf(fmaf(acc.w, d, b.w), 0.f);
    *(float4*)(out + (size_t)v * 256 + l * 4) = o;
}

// ---------------- GEMM: 128x128 tile, 8x8 per thread, BK=32, M(out cols)=256 ----------------
// EPI 0: C[r,c] = dinv[r] * acc      (layer-2 pre-aggregation scaling)
// EPI 1: C[r,c] = relu(acc + bias[c]) (layer-1 post-GEMM epilogue)

template<int EPI>
__global__ __launch_bounds__(256) void k_gemm(
    const float* __restrict__ A, const float* __restrict__ W,
    const float* __restrict__ dinv, const float* __restrict__ bias,
    float* __restrict__ C, int Nrows, int K) {
    __shared__ float As[32][132];  // [k][row], padded
    __shared__ float Ws[32][132];  // [k][col], padded
    int row0 = blockIdx.x * 128, col0 = blockIdx.y * 128;
    int tid = threadIdx.x;
    int tx = tid & 15, ty = tid >> 4;
    float acc[8][8] = {};
    for (int k0 = 0; k0 < K; k0 += 32) {
        // A tile: 128 rows x 32 k = 1024 float4, 4 per thread (transpose into As[k][row])
#pragma unroll
        for (int i = 0; i < 4; ++i) {
            int idx = i * 256 + tid;
            int r = idx >> 3;
            int c4 = (idx & 7) * 4;
            int gr = row0 + r;
            float4 v = make_float4(0.f, 0.f, 0.f, 0.f);
            if (gr < Nrows) v = *(const float4*)&A[(size_t)gr * K + k0 + c4];
            As[c4 + 0][r] = v.x;
            As[c4 + 1][r] = v.y;
            As[c4 + 2][r] = v.z;
            As[c4 + 3][r] = v.w;
        }
        // W tile: 32 k x 128 cols = 1024 float4, 4 per thread (direct)
#pragma unroll
        for (int i = 0; i < 4; ++i) {
            int idx = i * 256 + tid;
            int kr = idx >> 5;
            int c4 = (idx & 31) * 4;
            *(float4*)&Ws[kr][c4] = *(const float4*)&W[(size_t)(k0 + kr) * 256 + col0 + c4];
        }
        __syncthreads();
#pragma unroll
        for (int kk = 0; kk < 32; ++kk) {
            float a[8], b[8];
            *(float4*)&a[0] = *(const float4*)&As[kk][ty * 4];
            *(float4*)&a[4] = *(const float4*)&As[kk][64 + ty * 4];
            *(float4*)&b[0] = *(const float4*)&Ws[kk][tx * 4];
            *(float4*)&b[4] = *(const float4*)&Ws[kk][64 + tx * 4];
#pragma unroll
            for (int i = 0; i < 8; ++i)
#pragma unroll
                for (int j = 0; j < 8; ++j) acc[i][j] = fmaf(a[i], b[j], acc[i][j]);
        }
        __syncthreads();
    }
#pragma unroll
    for (int ih = 0; ih < 2; ++ih) {
#pragma unroll
        for (int i = 0; i < 4; ++i) {
            int r = row0 + ih * 64 + ty * 4 + i;
            if (r >= Nrows) continue;
            float sc = (EPI == 0) ? dinv[r] : 0.f;
#pragma unroll
            for (int jh = 0; jh < 2; ++jh) {
                int c = col0 + jh * 64 + tx * 4;
                float4 o;
                if (EPI == 0) {
                    o.x = acc[ih * 4 + i][jh * 4 + 0] * sc;
                    o.y = acc[ih * 4 + i][jh * 4 + 1] * sc;
                    o.z = acc[ih * 4 + i][jh * 4 + 2] * sc;
                    o.w = acc[ih * 4 + i][jh * 4 + 3] * sc;
                } else {
                    float4 b = *(const float4*)&bias[c];
                    o.x = fmaxf(acc[ih * 4 + i][jh * 4 + 0] + b.x, 0.f);
                    o.y = fmaxf(acc[ih * 4 + i][jh * 4 + 1] + b.y, 0.f);
                    o.z = fmaxf(acc[ih * 4 + i][jh * 4 + 2] + b.z, 0.f);
                    o.w = fmaxf(acc[ih * 4 + i][jh * 4 + 3] + b.w, 0.f);
                }
                *(float4*)&C[(size_t)r * 256 + c] = o;
            }
        }
    }
}

// ---------------- pooled mean + linear head ----------------

__global__ __launch_bounds__(256) void k_pool_head(
    const float* __restrict__ h2, const int* __restrict__ gstart,
    const float* __restrict__ Wl, const float* __restrict__ bl,
    float* __restrict__ out, int G) {
    int g = blockIdx.x;
    int t = threadIdx.x;
    int i0 = gstart[g], i1 = gstart[g + 1];
    float s = 0.f;
    for (int i = i0; i < i1; ++i) s += h2[(size_t)i * 256 + t];
    float cnt = (float)(i1 - i0);
    float pooled = s / fmaxf(cnt, 1.f);
    float v = pooled * Wl[t];
#pragma unroll
    for (int off = 32; off > 0; off >>= 1) v += __shfl_down(v, off, 64);
    __shared__ float red[4];
    if ((t & 63) == 0) red[t >> 6] = v;
    __syncthreads();
    if (t == 0) out[g] = red[0] + red[1] + red[2] + red[3] + bl[0];
}

// ---------------- launch ----------------

extern "C" void kernel_launch(void* const* d_in, const int* in_sizes, int n_in,
                              void* d_out, int out_size, void* d_ws, size_t ws_size,
                              hipStream_t stream) {
    const float* x  = (const float*)d_in[0];
    const int* ei   = (const int*)d_in[1];
    const int* batch= (const int*)d_in[2];
    const float* W1 = (const float*)d_in[3];
    const float* b1 = (const float*)d_in[4];
    const float* W2 = (const float*)d_in[5];
    const float* b2 = (const float*)d_in[6];
    const float* Wl = (const float*)d_in[7];
    const float* bl = (const float*)d_in[8];
    float* out = (float*)d_out;

    const int N = in_sizes[2];
    const int E = in_sizes[1] / 2;
    const int G = out_size;
    const int DIN = in_sizes[0] / N;    // 128
    const int DH = 256;
    (void)DIN; (void)DH;

    char* wsp = (char*)d_ws;
    size_t off = 0;
    auto carve = [&](size_t bytes) -> void* {
        void* p = wsp + off;
        off = (off + bytes + 255) & ~(size_t)255;
        return p;
    };
    float* buf1    = (float*)carve((size_t)N * 256 * 4);  // xa (N x 128) then hs (N x 256)
    float* buf2    = (float*)carve((size_t)N * 256 * 4);  // hb=h1 then h2
    float* dinv    = (float*)carve((size_t)N * 4);
    int* ecnt      = (int*)carve((size_t)N * 4);
    int* rowstart  = (int*)carve((size_t)(N + 1) * 4);
    int* cursor    = (int*)carve((size_t)N * 4);
    int* ssrc      = (int*)carve((size_t)E * 4);
    const int NB = (N + 1023) / 1024;
    int* bsum      = (int*)carve((size_t)NB * 4);
    int* boff      = (int*)carve((size_t)NB * 4);
    int* gstart    = (int*)carve((size_t)(G + 1) * 4);
    (void)ws_size;

    const int* esrc = ei;
    const int* edst = ei + E;

    int nb256 = (N + 255) / 256;
    int eb256 = (E + 255) / 256;

    hipLaunchKernelGGL(k_init, dim3(nb256), dim3(256), 0, stream, ecnt, cursor, N);
    hipLaunchKernelGGL(k_edge_count, dim3(eb256), dim3(256), 0, stream, edst, ecnt, E);
    hipLaunchKernelGGL(k_scanA, dim3(NB), dim3(256), 0, stream, ecnt, bsum, N);
    hipLaunchKernelGGL(k_scanB, dim3(1), dim3(256), 0, stream, bsum, boff, NB);
    hipLaunchKernelGGL(k_scanC, dim3(NB), dim3(256), 0, stream, ecnt, boff, rowstart, dinv, N);
    hipLaunchKernelGGL(k_tail, dim3(1), dim3(1), 0, stream, rowstart, N, E);
    hipLaunchKernelGGL(k_scatter, dim3(eb256), dim3(256), 0, stream, esrc, edst, rowstart, cursor, ssrc, E);
    hipLaunchKernelGGL(k_gstarts, dim3(nb256), dim3(256), 0, stream, batch, gstart, N, G);

    // layer 1: xa = Ahat x   (into buf1);  h1 = relu(xa @ W1 + b1)  (into buf2)
    hipLaunchKernelGGL(k_agg_in, dim3((N + 7) / 8), dim3(256), 0, stream,
                       x, rowstart, ssrc, dinv, buf1, N);
    hipLaunchKernelGGL((k_gemm<1>), dim3((N + 127) / 128, 2), dim3(256), 0, stream,
                       buf1, W1, (const float*)nullptr, b1, buf2, N, 128);
    // layer 2: hs = dinv * (h1 @ W2)  (into buf1);  h2 = relu(dinv*(agg hs) + b2) (into buf2)
    hipLaunchKernelGGL((k_gemm<0>), dim3((N + 127) / 128, 2), dim3(256), 0, stream,
                       buf2, W2, dinv, (const float*)nullptr, buf1, N, 256);
    hipLaunchKernelGGL(k_aggregate, dim3((N + 3) / 4), dim3(256), 0, stream,
                       buf1, rowstart, ssrc, dinv, b2, buf2, N);
    // pool + head
    hipLaunchKernelGGL(k_pool_head, dim3(G), dim3(256), 0, stream, buf2, gstart, Wl, bl, out, G);
}

// Round 4
// 722.533 us; speedup vs baseline: 1.3396x; 1.1843x over previous
//
#include <hip/hip_runtime.h>
#include <hip/hip_fp16.h>
#include <math.h>

// ---------------- graph preprocessing ----------------

__global__ void k_init(int* __restrict__ ecnt, int* __restrict__ cursor, int N) {
    int i = blockIdx.x * 256 + threadIdx.x;
    if (i < N) { ecnt[i] = 0; cursor[i] = 0; }
}

__global__ void k_edge_count(const int* __restrict__ dst, int* __restrict__ ecnt, int E) {
    int i = blockIdx.x * 256 + threadIdx.x;
    if (i < E) atomicAdd(&ecnt[dst[i]], 1);
}

__global__ void k_scanA(const int* __restrict__ ecnt, int* __restrict__ bsum, int N) {
    int t = threadIdx.x;
    int base = blockIdx.x * 1024;
    int s = 0;
#pragma unroll
    for (int j = 0; j < 4; ++j) {
        int i = base + j * 256 + t;
        if (i < N) s += ecnt[i];
    }
#pragma unroll
    for (int off = 32; off > 0; off >>= 1) s += __shfl_down(s, off, 64);
    __shared__ int wsum[4];
    if ((t & 63) == 0) wsum[t >> 6] = s;
    __syncthreads();
    if (t == 0) bsum[blockIdx.x] = wsum[0] + wsum[1] + wsum[2] + wsum[3];
}

__global__ void k_scanB(const int* __restrict__ bsum, int* __restrict__ boff, int NB) {
    __shared__ int sh[256];
    int t = threadIdx.x;
    int v = (t < NB) ? bsum[t] : 0;
    sh[t] = v;
    __syncthreads();
    for (int off = 1; off < 256; off <<= 1) {
        int u = (t >= off) ? sh[t - off] : 0;
        __syncthreads();
        sh[t] += u;
        __syncthreads();
    }
    if (t < NB) boff[t] = sh[t] - v;  // exclusive
}

__global__ void k_scanC(const int* __restrict__ ecnt, const int* __restrict__ boff,
                        int* __restrict__ rowstart, float* __restrict__ dinv, int N) {
    int t = threadIdx.x;
    int base = blockIdx.x * 1024 + t * 4;
    int e[4];
    int s = 0;
#pragma unroll
    for (int j = 0; j < 4; ++j) {
        int i = base + j;
        e[j] = (i < N) ? ecnt[i] : 0;
        s += e[j];
    }
    __shared__ int sh[256];
    sh[t] = s;
    __syncthreads();
    for (int off = 1; off < 256; off <<= 1) {
        int u = (t >= off) ? sh[t - off] : 0;
        __syncthreads();
        sh[t] += u;
        __syncthreads();
    }
    int off0 = boff[blockIdx.x] + sh[t] - s;
    int run = 0;
#pragma unroll
    for (int j = 0; j < 4; ++j) {
        int i = base + j;
        if (i < N) {
            rowstart[i] = off0 + run;
            dinv[i] = rsqrtf((float)(e[j] + 1));  // +1 self loop
        }
        run += e[j];
    }
}

__global__ void k_tail(int* __restrict__ rowstart, int N, int E) {
    rowstart[N] = E;
}

__global__ void k_scatter(const int* __restrict__ src, const int* __restrict__ dst,
                          const int* __restrict__ rowstart, int* __restrict__ cursor,
                          int* __restrict__ ssrc, int E) {
    int i = blockIdx.x * 256 + threadIdx.x;
    if (i < E) {
        int v = dst[i];
        int p = rowstart[v] + atomicAdd(&cursor[v], 1);
        ssrc[p] = src[i];
    }
}

__global__ void k_gstarts(const int* __restrict__ batch, int* __restrict__ gstart, int N, int G) {
    int i = blockIdx.x * 256 + threadIdx.x;
    if (i >= N) return;
    int bi = batch[i];
    int bp = (i == 0) ? -1 : batch[i - 1];
    for (int g = bp + 1; g <= bi; ++g) gstart[g] = i;
    if (i == N - 1) {
        for (int g = bi + 1; g <= G; ++g) gstart[g] = N;
    }
}

// ---------------- f32 -> f16 cast (streaming) ----------------

__global__ __launch_bounds__(256) void k_cast_f2h(const float* __restrict__ in,
                                                  __half* __restrict__ out, int n4) {
    int i = blockIdx.x * 256 + threadIdx.x;
    if (i >= n4) return;
    float4 v = *(const float4*)(in + (size_t)i * 4);
    __half2 a = __floats2half2_rn(v.x, v.y);
    __half2 b = __floats2half2_rn(v.z, v.w);
    union { __half2 h[2]; float2 f; } u;
    u.h[0] = a; u.h[1] = b;
    *(float2*)(out + (size_t)i * 4) = u.f;
}

// ---------------- layer-1 input aggregation ----------------
// xa[v] = dinv[v]*(dinv[v]*x[v] + sum dinv[u]*xh[u]); xh fp16, 128 dims
// half-wave (32 lanes) per node, 4 halves (8B) per lane

__device__ __forceinline__ void acc_h4(float4& acc, float2 raw, float d) {
    union { float2 f; __half2 h[2]; } u;
    u.f = raw;
    float2 p0 = __half22float2(u.h[0]);
    float2 p1 = __half22float2(u.h[1]);
    acc.x = fmaf(p0.x, d, acc.x);
    acc.y = fmaf(p0.y, d, acc.y);
    acc.z = fmaf(p1.x, d, acc.z);
    acc.w = fmaf(p1.y, d, acc.w);
}

__global__ __launch_bounds__(256) void k_agg_in(
    const float* __restrict__ x, const __half* __restrict__ xh,
    const int* __restrict__ rowstart, const int* __restrict__ ssrc,
    const float* __restrict__ dinv, float* __restrict__ xa, int N) {
    int half_id = threadIdx.x >> 5;
    int l = threadIdx.x & 31;
    int v = blockIdx.x * 8 + half_id;
    if (v >= N) return;
    float dv = dinv[v];
    float4 s = *(const float4*)(x + (size_t)v * 128 + l * 4);
    float4 acc = make_float4(s.x * dv, s.y * dv, s.z * dv, s.w * dv);
    int e = rowstart[v], e1 = rowstart[v + 1];
    for (; e + 4 <= e1; e += 4) {
        int u0 = ssrc[e], u1 = ssrc[e + 1], u2 = ssrc[e + 2], u3 = ssrc[e + 3];
        float d0 = dinv[u0], d1 = dinv[u1], d2 = dinv[u2], d3 = dinv[u3];
        float2 m0 = *(const float2*)(xh + (size_t)u0 * 128 + l * 4);
        float2 m1 = *(const float2*)(xh + (size_t)u1 * 128 + l * 4);
        float2 m2 = *(const float2*)(xh + (size_t)u2 * 128 + l * 4);
        float2 m3 = *(const float2*)(xh + (size_t)u3 * 128 + l * 4);
        acc_h4(acc, m0, d0);
        acc_h4(acc, m1, d1);
        acc_h4(acc, m2, d2);
        acc_h4(acc, m3, d3);
    }
    for (; e < e1; ++e) {
        int u = ssrc[e];
        float d = dinv[u];
        float2 m = *(const float2*)(xh + (size_t)u * 128 + l * 4);
        acc_h4(acc, m, d);
    }
    float4 o = make_float4(acc.x * dv, acc.y * dv, acc.z * dv, acc.w * dv);
    *(float4*)(xa + (size_t)v * 128 + l * 4) = o;
}

// ---------------- layer-2 aggregation ----------------
// out[v] = relu(dinv[v]*(hsh[v] + sum hsh[u]) + b); hsh fp16, 256 dims
// one wave per node, 4 halves (8B) per lane

__device__ __forceinline__ void acc_h4s(float4& acc, float2 raw) {
    union { float2 f; __half2 h[2]; } u;
    u.f = raw;
    float2 p0 = __half22float2(u.h[0]);
    float2 p1 = __half22float2(u.h[1]);
    acc.x += p0.x; acc.y += p0.y; acc.z += p1.x; acc.w += p1.y;
}

__global__ __launch_bounds__(256) void k_aggregate(
    const __half* __restrict__ hsh, const int* __restrict__ rowstart,
    const int* __restrict__ ssrc, const float* __restrict__ dinv,
    const float* __restrict__ bias, float* __restrict__ out, int N) {
    int w = threadIdx.x >> 6;
    int l = threadIdx.x & 63;
    int v = blockIdx.x * 4 + w;
    if (v >= N) return;
    float4 acc = make_float4(0.f, 0.f, 0.f, 0.f);
    acc_h4s(acc, *(const float2*)(hsh + (size_t)v * 256 + l * 4));  // self loop
    int e = rowstart[v], e1 = rowstart[v + 1];
    for (; e + 4 <= e1; e += 4) {
        int u0 = ssrc[e], u1 = ssrc[e + 1], u2 = ssrc[e + 2], u3 = ssrc[e + 3];
        float2 m0 = *(const float2*)(hsh + (size_t)u0 * 256 + l * 4);
        float2 m1 = *(const float2*)(hsh + (size_t)u1 * 256 + l * 4);
        float2 m2 = *(const float2*)(hsh + (size_t)u2 * 256 + l * 4);
        float2 m3 = *(const float2*)(hsh + (size_t)u3 * 256 + l * 4);
        acc_h4s(acc, m0);
        acc_h4s(acc, m1);
        acc_h4s(acc, m2);
        acc_h4s(acc, m3);
    }
    for (; e < e1; ++e) {
        int u = ssrc[e];
        acc_h4s(acc, *(const float2*)(hsh + (size_t)u * 256 + l * 4));
    }
    float d = dinv[v];
    float4 b = *(const float4*)(bias + l * 4);
    float4 o;
    o.x = fmaxf(fmaf(acc.x, d, b.x), 0.f);
    o.y = fmaxf(fmaf(acc.y, d, b.y), 0.f);
    o.z = fmaxf(fmaf(acc.z, d, b.z), 0.f);
    o.w = fmaxf(fmaf(acc.w, d, b.w), 0.f);
    *(float4*)(out + (size_t)v * 256 + l * 4) = o;
}

// ---------------- GEMM: 128x128 tile, 8x8 per thread, BK=32, out cols = 256 ----------------
// EPI 0: hs_h[r,c] = (half)(dinv[r] * acc)     (layer-2 pre-aggregation, fp16 out)
// EPI 1: C[r,c]    = relu(acc + bias[c])       (layer-1 epilogue, f32 out)

template<int EPI>
__global__ __launch_bounds__(256) void k_gemm(
    const float* __restrict__ A, const float* __restrict__ W,
    const float* __restrict__ dinv, const float* __restrict__ bias,
    void* __restrict__ Cout, int Nrows, int K) {
    __shared__ float As[32][132];  // [k][row], padded
    __shared__ float Ws[32][132];  // [k][col], padded
    int row0 = blockIdx.x * 128, col0 = blockIdx.y * 128;
    int tid = threadIdx.x;
    int tx = tid & 15, ty = tid >> 4;
    float acc[8][8] = {};
    for (int k0 = 0; k0 < K; k0 += 32) {
#pragma unroll
        for (int i = 0; i < 4; ++i) {
            int idx = i * 256 + tid;
            int r = idx >> 3;
            int c4 = (idx & 7) * 4;
            int gr = row0 + r;
            float4 v = make_float4(0.f, 0.f, 0.f, 0.f);
            if (gr < Nrows) v = *(const float4*)&A[(size_t)gr * K + k0 + c4];
            As[c4 + 0][r] = v.x;
            As[c4 + 1][r] = v.y;
            As[c4 + 2][r] = v.z;
            As[c4 + 3][r] = v.w;
        }
#pragma unroll
        for (int i = 0; i < 4; ++i) {
            int idx = i * 256 + tid;
            int kr = idx >> 5;
            int c4 = (idx & 31) * 4;
            *(float4*)&Ws[kr][c4] = *(const float4*)&W[(size_t)(k0 + kr) * 256 + col0 + c4];
        }
        __syncthreads();
#pragma unroll
        for (int kk = 0; kk < 32; ++kk) {
            float a[8], b[8];
            *(float4*)&a[0] = *(const float4*)&As[kk][ty * 4];
            *(float4*)&a[4] = *(const float4*)&As[kk][64 + ty * 4];
            *(float4*)&b[0] = *(const float4*)&Ws[kk][tx * 4];
            *(float4*)&b[4] = *(const float4*)&Ws[kk][64 + tx * 4];
#pragma unroll
            for (int i = 0; i < 8; ++i)
#pragma unroll
                for (int j = 0; j < 8; ++j) acc[i][j] = fmaf(a[i], b[j], acc[i][j]);
        }
        __syncthreads();
    }
#pragma unroll
    for (int ih = 0; ih < 2; ++ih) {
#pragma unroll
        for (int i = 0; i < 4; ++i) {
            int r = row0 + ih * 64 + ty * 4 + i;
            if (r >= Nrows) continue;
            float sc = (EPI == 0) ? dinv[r] : 0.f;
#pragma unroll
            for (int jh = 0; jh < 2; ++jh) {
                int c = col0 + jh * 64 + tx * 4;
                if (EPI == 0) {
                    __half* Ch = (__half*)Cout;
                    union { __half2 h[2]; float2 f; } u;
                    u.h[0] = __floats2half2_rn(acc[ih * 4 + i][jh * 4 + 0] * sc,
                                               acc[ih * 4 + i][jh * 4 + 1] * sc);
                    u.h[1] = __floats2half2_rn(acc[ih * 4 + i][jh * 4 + 2] * sc,
                                               acc[ih * 4 + i][jh * 4 + 3] * sc);
                    *(float2*)&Ch[(size_t)r * 256 + c] = u.f;
                } else {
                    float* Cf = (float*)Cout;
                    float4 b = *(const float4*)&bias[c];
                    float4 o;
                    o.x = fmaxf(acc[ih * 4 + i][jh * 4 + 0] + b.x, 0.f);
                    o.y = fmaxf(acc[ih * 4 + i][jh * 4 + 1] + b.y, 0.f);
                    o.z = fmaxf(acc[ih * 4 + i][jh * 4 + 2] + b.z, 0.f);
                    o.w = fmaxf(acc[ih * 4 + i][jh * 4 + 3] + b.w, 0.f);
                    *(float4*)&Cf[(size_t)r * 256 + c] = o;
                }
            }
        }
    }
}

// ---------------- pooled mean + linear head ----------------

__global__ __launch_bounds__(256) void k_pool_head(
    const float* __restrict__ h2, const int* __restrict__ gstart,
    const float* __restrict__ Wl, const float* __restrict__ bl,
    float* __restrict__ out, int G) {
    int g = blockIdx.x;
    int t = threadIdx.x;
    int i0 = gstart[g], i1 = gstart[g + 1];
    float s = 0.f;
    for (int i = i0; i < i1; ++i) s += h2[(size_t)i * 256 + t];
    float cnt = (float)(i1 - i0);
    float pooled = s / fmaxf(cnt, 1.f);
    float v = pooled * Wl[t];
#pragma unroll
    for (int off = 32; off > 0; off >>= 1) v += __shfl_down(v, off, 64);
    __shared__ float red[4];
    if ((t & 63) == 0) red[t >> 6] = v;
    __syncthreads();
    if (t == 0) out[g] = red[0] + red[1] + red[2] + red[3] + bl[0];
}

// ---------------- launch ----------------

extern "C" void kernel_launch(void* const* d_in, const int* in_sizes, int n_in,
                              void* d_out, int out_size, void* d_ws, size_t ws_size,
                              hipStream_t stream) {
    const float* x  = (const float*)d_in[0];
    const int* ei   = (const int*)d_in[1];
    const int* batch= (const int*)d_in[2];
    const float* W1 = (const float*)d_in[3];
    const float* b1 = (const float*)d_in[4];
    const float* W2 = (const float*)d_in[5];
    const float* b2 = (const float*)d_in[6];
    const float* Wl = (const float*)d_in[7];
    const float* bl = (const float*)d_in[8];
    float* out = (float*)d_out;

    const int N = in_sizes[2];
    const int E = in_sizes[1] / 2;
    const int G = out_size;

    // Workspace budget note: R2's ~213 MB layout passed; R3's +77 MB of
    // dedicated fp16 buffers crashed (ws overflow). So the fp16 buffers
    // alias dead regions of buf1 — total footprint identical to R2.
    char* wsp = (char*)d_ws;
    size_t off = 0;
    auto carve = [&](size_t bytes) -> void* {
        void* p = wsp + off;
        off = (off + bytes + 255) & ~(size_t)255;
        return p;
    };
    float* buf1    = (float*)carve((size_t)N * 256 * 4);  // xa (low half) + xh (high half); later hsh (low half)
    float* buf2    = (float*)carve((size_t)N * 256 * 4);  // h1, then h2
    float* dinv    = (float*)carve((size_t)N * 4);
    int* ecnt      = (int*)carve((size_t)N * 4);
    int* rowstart  = (int*)carve((size_t)(N + 1) * 4);
    int* cursor    = (int*)carve((size_t)N * 4);
    int* ssrc      = (int*)carve((size_t)E * 4);
    const int NB = (N + 1023) / 1024;
    int* bsum      = (int*)carve((size_t)NB * 4);
    int* boff      = (int*)carve((size_t)NB * 4);
    int* gstart    = (int*)carve((size_t)(G + 1) * 4);
    (void)ws_size;

    // aliases into buf1 (liveness-checked):
    float*  xa  = buf1;                               // N x 128 f32, low half
    __half* xh  = (__half*)(buf1 + (size_t)N * 128);  // N x 128 f16, high half (lives with xa)
    __half* hsh = (__half*)buf1;                      // N x 256 f16, low half (after xa dead)
    float*  h1  = buf2;                               // N x 256 f32
    float*  h2  = buf2;                               // N x 256 f32 (after h1 dead)

    const int* esrc = ei;
    const int* edst = ei + E;

    int nb256 = (N + 255) / 256;
    int eb256 = (E + 255) / 256;

    hipLaunchKernelGGL(k_init, dim3(nb256), dim3(256), 0, stream, ecnt, cursor, N);
    hipLaunchKernelGGL(k_edge_count, dim3(eb256), dim3(256), 0, stream, edst, ecnt, E);
    hipLaunchKernelGGL(k_scanA, dim3(NB), dim3(256), 0, stream, ecnt, bsum, N);
    hipLaunchKernelGGL(k_scanB, dim3(1), dim3(256), 0, stream, bsum, boff, NB);
    hipLaunchKernelGGL(k_scanC, dim3(NB), dim3(256), 0, stream, ecnt, boff, rowstart, dinv, N);
    hipLaunchKernelGGL(k_tail, dim3(1), dim3(1), 0, stream, rowstart, N, E);
    hipLaunchKernelGGL(k_scatter, dim3(eb256), dim3(256), 0, stream, esrc, edst, rowstart, cursor, ssrc, E);
    hipLaunchKernelGGL(k_gstarts, dim3(nb256), dim3(256), 0, stream, batch, gstart, N, G);
    hipLaunchKernelGGL(k_cast_f2h, dim3((N * 32 + 255) / 256), dim3(256), 0, stream,
                       x, xh, N * 32);

    // layer 1: xa = Ahat x (fp16 gather); h1 = relu(xa @ W1 + b1)
    hipLaunchKernelGGL(k_agg_in, dim3((N + 7) / 8), dim3(256), 0, stream,
                       x, xh, rowstart, ssrc, dinv, xa, N);
    hipLaunchKernelGGL((k_gemm<1>), dim3((N + 127) / 128, 2), dim3(256), 0, stream,
                       xa, W1, (const float*)nullptr, b1, (void*)h1, N, 128);
    // layer 2: hsh = (half)(dinv * (h1 @ W2)); h2 = relu(dinv*(agg hsh) + b2)
    hipLaunchKernelGGL((k_gemm<0>), dim3((N + 127) / 128, 2), dim3(256), 0, stream,
                       h1, W2, dinv, (const float*)nullptr, (void*)hsh, N, 256);
    hipLaunchKernelGGL(k_aggregate, dim3((N + 3) / 4), dim3(256), 0, stream,
                       hsh, rowstart, ssrc, dinv, b2, h2, N);
    // pool + head
    hipLaunchKernelGGL(k_pool_head, dim3(G), dim3(256), 0, stream, h2, gstart, Wl, bl, out, G);
}

// Round 5
// 493.189 us; speedup vs baseline: 1.9626x; 1.4650x over previous
//
#include <hip/hip_runtime.h>
#include <hip/hip_fp16.h>
#include <math.h>

typedef _Float16 f16x8 __attribute__((ext_vector_type(8)));
typedef float f32x4 __attribute__((ext_vector_type(4)));

// ---------------- graph preprocessing ----------------

__global__ void k_init(int* __restrict__ ecnt, int* __restrict__ cursor, int N) {
    int i = blockIdx.x * 256 + threadIdx.x;
    if (i < N) { ecnt[i] = 0; cursor[i] = 0; }
}

__global__ void k_edge_count(const int* __restrict__ dst, int* __restrict__ ecnt, int E) {
    int i = blockIdx.x * 256 + threadIdx.x;
    if (i < E) atomicAdd(&ecnt[dst[i]], 1);
}

__global__ void k_scanA(const int* __restrict__ ecnt, int* __restrict__ bsum, int N) {
    int t = threadIdx.x;
    int base = blockIdx.x * 1024;
    int s = 0;
#pragma unroll
    for (int j = 0; j < 4; ++j) {
        int i = base + j * 256 + t;
        if (i < N) s += ecnt[i];
    }
#pragma unroll
    for (int off = 32; off > 0; off >>= 1) s += __shfl_down(s, off, 64);
    __shared__ int wsum[4];
    if ((t & 63) == 0) wsum[t >> 6] = s;
    __syncthreads();
    if (t == 0) bsum[blockIdx.x] = wsum[0] + wsum[1] + wsum[2] + wsum[3];
}

__global__ void k_scanB(const int* __restrict__ bsum, int* __restrict__ boff, int NB) {
    __shared__ int sh[256];
    int t = threadIdx.x;
    int v = (t < NB) ? bsum[t] : 0;
    sh[t] = v;
    __syncthreads();
    for (int off = 1; off < 256; off <<= 1) {
        int u = (t >= off) ? sh[t - off] : 0;
        __syncthreads();
        sh[t] += u;
        __syncthreads();
    }
    if (t < NB) boff[t] = sh[t] - v;  // exclusive
}

__global__ void k_scanC(const int* __restrict__ ecnt, const int* __restrict__ boff,
                        int* __restrict__ rowstart, float* __restrict__ dinv, int N) {
    int t = threadIdx.x;
    int base = blockIdx.x * 1024 + t * 4;
    int e[4];
    int s = 0;
#pragma unroll
    for (int j = 0; j < 4; ++j) {
        int i = base + j;
        e[j] = (i < N) ? ecnt[i] : 0;
        s += e[j];
    }
    __shared__ int sh[256];
    sh[t] = s;
    __syncthreads();
    for (int off = 1; off < 256; off <<= 1) {
        int u = (t >= off) ? sh[t - off] : 0;
        __syncthreads();
        sh[t] += u;
        __syncthreads();
    }
    int off0 = boff[blockIdx.x] + sh[t] - s;
    int run = 0;
#pragma unroll
    for (int j = 0; j < 4; ++j) {
        int i = base + j;
        if (i < N) {
            rowstart[i] = off0 + run;
            dinv[i] = rsqrtf((float)(e[j] + 1));  // +1 self loop
        }
        run += e[j];
    }
}

__global__ void k_tail(int* __restrict__ rowstart, int N, int E) {
    rowstart[N] = E;
}

__global__ void k_scatter(const int* __restrict__ src, const int* __restrict__ dst,
                          const int* __restrict__ rowstart, int* __restrict__ cursor,
                          int* __restrict__ ssrc, int E) {
    int i = blockIdx.x * 256 + threadIdx.x;
    if (i < E) {
        int v = dst[i];
        int p = rowstart[v] + atomicAdd(&cursor[v], 1);
        ssrc[p] = src[i];
    }
}

__global__ void k_gstarts(const int* __restrict__ batch, int* __restrict__ gstart, int N, int G) {
    int i = blockIdx.x * 256 + threadIdx.x;
    if (i >= N) return;
    int bi = batch[i];
    int bp = (i == 0) ? -1 : batch[i - 1];
    for (int g = bp + 1; g <= bi; ++g) gstart[g] = i;
    if (i == N - 1) {
        for (int g = bi + 1; g <= G; ++g) gstart[g] = N;
    }
}

// ---------------- f32 -> f16 cast (streaming) ----------------

__global__ __launch_bounds__(256) void k_cast_f2h(const float* __restrict__ in,
                                                  __half* __restrict__ out, int n4) {
    int i = blockIdx.x * 256 + threadIdx.x;
    if (i >= n4) return;
    float4 v = *(const float4*)(in + (size_t)i * 4);
    __half2 a = __floats2half2_rn(v.x, v.y);
    __half2 b = __floats2half2_rn(v.z, v.w);
    union { __half2 h[2]; float2 f; } u;
    u.h[0] = a; u.h[1] = b;
    *(float2*)(out + (size_t)i * 4) = u.f;
}

// ---------------- weight transpose + cast: W[K][256] f32 -> Wt[256][K] f16 ----------------

__global__ __launch_bounds__(256) void k_wt(const float* __restrict__ W,
                                            _Float16* __restrict__ Wt, int K) {
    int idx = blockIdx.x * 256 + threadIdx.x;
    if (idx >= K * 256) return;
    int c = idx / K, k = idx - c * K;
    Wt[idx] = (_Float16)W[k * 256 + c];
}

// ---------------- layer-1 input aggregation ----------------
// xa_h[v] = (half) dinv[v]*(dinv[v]*x[v] + sum dinv[u]*xh[u]); 128 dims
// half-wave (32 lanes) per node

__device__ __forceinline__ void acc_h4(float4& acc, float2 raw, float d) {
    union { float2 f; __half2 h[2]; } u;
    u.f = raw;
    float2 p0 = __half22float2(u.h[0]);
    float2 p1 = __half22float2(u.h[1]);
    acc.x = fmaf(p0.x, d, acc.x);
    acc.y = fmaf(p0.y, d, acc.y);
    acc.z = fmaf(p1.x, d, acc.z);
    acc.w = fmaf(p1.y, d, acc.w);
}

__global__ __launch_bounds__(256) void k_agg_in(
    const float* __restrict__ x, const __half* __restrict__ xh,
    const int* __restrict__ rowstart, const int* __restrict__ ssrc,
    const float* __restrict__ dinv, __half* __restrict__ xa_h, int N) {
    int half_id = threadIdx.x >> 5;
    int l = threadIdx.x & 31;
    int v = blockIdx.x * 8 + half_id;
    if (v >= N) return;
    float dv = dinv[v];
    float4 s = *(const float4*)(x + (size_t)v * 128 + l * 4);
    float4 acc = make_float4(s.x * dv, s.y * dv, s.z * dv, s.w * dv);
    int e = rowstart[v], e1 = rowstart[v + 1];
    for (; e + 4 <= e1; e += 4) {
        int u0 = ssrc[e], u1 = ssrc[e + 1], u2 = ssrc[e + 2], u3 = ssrc[e + 3];
        float d0 = dinv[u0], d1 = dinv[u1], d2 = dinv[u2], d3 = dinv[u3];
        float2 m0 = *(const float2*)(xh + (size_t)u0 * 128 + l * 4);
        float2 m1 = *(const float2*)(xh + (size_t)u1 * 128 + l * 4);
        float2 m2 = *(const float2*)(xh + (size_t)u2 * 128 + l * 4);
        float2 m3 = *(const float2*)(xh + (size_t)u3 * 128 + l * 4);
        acc_h4(acc, m0, d0);
        acc_h4(acc, m1, d1);
        acc_h4(acc, m2, d2);
        acc_h4(acc, m3, d3);
    }
    for (; e < e1; ++e) {
        int u = ssrc[e];
        float d = dinv[u];
        float2 m = *(const float2*)(xh + (size_t)u * 128 + l * 4);
        acc_h4(acc, m, d);
    }
    union { __half2 h[2]; float2 f; } uo;
    uo.h[0] = __floats2half2_rn(acc.x * dv, acc.y * dv);
    uo.h[1] = __floats2half2_rn(acc.z * dv, acc.w * dv);
    *(float2*)(xa_h + (size_t)v * 128 + l * 4) = uo.f;
}

// ---------------- layer-2 aggregation ----------------
// out[v] = relu(dinv[v]*(hsh[v] + sum hsh[u]) + b); hsh fp16, 256 dims

__device__ __forceinline__ void acc_h4s(float4& acc, float2 raw) {
    union { float2 f; __half2 h[2]; } u;
    u.f = raw;
    float2 p0 = __half22float2(u.h[0]);
    float2 p1 = __half22float2(u.h[1]);
    acc.x += p0.x; acc.y += p0.y; acc.z += p1.x; acc.w += p1.y;
}

__global__ __launch_bounds__(256) void k_aggregate(
    const __half* __restrict__ hsh, const int* __restrict__ rowstart,
    const int* __restrict__ ssrc, const float* __restrict__ dinv,
    const float* __restrict__ bias, float* __restrict__ out, int N) {
    int w = threadIdx.x >> 6;
    int l = threadIdx.x & 63;
    int v = blockIdx.x * 4 + w;
    if (v >= N) return;
    float4 acc = make_float4(0.f, 0.f, 0.f, 0.f);
    acc_h4s(acc, *(const float2*)(hsh + (size_t)v * 256 + l * 4));  // self loop
    int e = rowstart[v], e1 = rowstart[v + 1];
    for (; e + 4 <= e1; e += 4) {
        int u0 = ssrc[e], u1 = ssrc[e + 1], u2 = ssrc[e + 2], u3 = ssrc[e + 3];
        float2 m0 = *(const float2*)(hsh + (size_t)u0 * 256 + l * 4);
        float2 m1 = *(const float2*)(hsh + (size_t)u1 * 256 + l * 4);
        float2 m2 = *(const float2*)(hsh + (size_t)u2 * 256 + l * 4);
        float2 m3 = *(const float2*)(hsh + (size_t)u3 * 256 + l * 4);
        acc_h4s(acc, m0);
        acc_h4s(acc, m1);
        acc_h4s(acc, m2);
        acc_h4s(acc, m3);
    }
    for (; e < e1; ++e) {
        int u = ssrc[e];
        acc_h4s(acc, *(const float2*)(hsh + (size_t)u * 256 + l * 4));
    }
    float d = dinv[v];
    float4 b = *(const float4*)(bias + l * 4);
    float4 o;
    o.x = fmaxf(fmaf(acc.x, d, b.x), 0.f);
    o.y = fmaxf(fmaf(acc.y, d, b.y), 0.f);
    o.z = fmaxf(fmaf(acc.z, d, b.z), 0.f);
    o.w = fmaxf(fmaf(acc.w, d, b.w), 0.f);
    *(float4*)(out + (size_t)v * 256 + l * 4) = o;
}

// ---------------- MFMA fp16 GEMM ----------------
// C[N x 256] = A[N x K] @ W[K x 256], A fp16, Wt[256][K] fp16 (pre-transposed), f32 accum.
// Block = 4 waves; wave w owns cols [64w, 64w+64) with B held in registers.
// Grid-stride over 64-row chunks; A tile staged to LDS via global_load_lds with
// pre-swizzled source (XOR bits 4-6 with row&7); swizzled ds_read_b128 a-frags.
// EPI 0: Ch = (half)(dinv[r] * acc)      EPI 1: Ch = (half)relu(acc + bias[c])

template<int K, int EPI>
__global__ __launch_bounds__(256, 2) void k_gemm_mfma(
    const _Float16* __restrict__ Ah, const _Float16* __restrict__ Wt,
    const float* __restrict__ dinv, const float* __restrict__ bias,
    _Float16* __restrict__ Ch, int Nrows, int nchunks) {
    constexpr int KS = K / 32;       // k-steps of 32
    constexpr int RB = 2 * K;        // row bytes in A / LDS tile
    constexpr int NLD = 64 * RB / 4096;  // global_load_lds issues per thread
    __shared__ _Float16 As[64 * K];

    int tid = threadIdx.x;
    int l = tid & 63;
    int wv = tid >> 6;

    // ---- B prologue: 4 col-tiles x KS k-steps, registers
    int bc = wv * 64 + (l & 15);
    int bk = (l >> 4) * 8;
    f16x8 breg[4][KS];
#pragma unroll
    for (int ct = 0; ct < 4; ++ct)
#pragma unroll
        for (int ks = 0; ks < KS; ++ks)
            breg[ct][ks] = *(const f16x8*)(Wt + (size_t)(bc + ct * 16) * K + ks * 32 + bk);
    float bb[4];
    if (EPI == 1) {
#pragma unroll
        for (int ct = 0; ct < 4; ++ct) bb[ct] = bias[bc + ct * 16];
    }

    for (int ch = blockIdx.x; ch < nchunks; ch += gridDim.x) {
        int r0 = ch * 64;
        // ---- stage A tile (64 x K fp16), source pre-swizzled, LDS linear
#pragma unroll
        for (int i = 0; i < NLD; ++i) {
            int logical = i * 4096 + tid * 16;
            int row = logical / RB;
            int colb = (logical & (RB - 1)) ^ ((row & 7) << 4);
            int grow = r0 + row;
            grow = grow < Nrows ? grow : Nrows - 1;
            const char* src = (const char*)Ah + (size_t)grow * RB + colb;
            char* dst = (char*)As + i * 4096 + wv * 1024;
            __builtin_amdgcn_global_load_lds(
                (const __attribute__((address_space(1))) void*)src,
                (__attribute__((address_space(3))) void*)dst, 16, 0, 0);
        }
        __syncthreads();   // compiler drains vmcnt before s_barrier

        // ---- compute: 4 row-blocks x KS x 4 col-tiles
#pragma unroll
        for (int rb = 0; rb < 4; ++rb) {
            f32x4 acc[4];
#pragma unroll
            for (int ct = 0; ct < 4; ++ct) acc[ct] = (f32x4){0.f, 0.f, 0.f, 0.f};
            int row = rb * 16 + (l & 15);
#pragma unroll
            for (int ks = 0; ks < KS; ++ks) {
                int lb = (row * RB + ks * 64 + (l >> 4) * 16) ^ ((l & 7) << 4);
                f16x8 a = *(const f16x8*)((const char*)As + lb);
#pragma unroll
                for (int ct = 0; ct < 4; ++ct)
                    acc[ct] = __builtin_amdgcn_mfma_f32_16x16x32_f16(a, breg[ct][ks], acc[ct], 0, 0, 0);
            }
            // ---- epilogue for this row-block
            int rbase = r0 + rb * 16 + (l >> 4) * 4;
#pragma unroll
            for (int j = 0; j < 4; ++j) {
                int r = rbase + j;
                if (r < Nrows) {
                    if (EPI == 0) {
                        float sc = dinv[r];
#pragma unroll
                        for (int ct = 0; ct < 4; ++ct)
                            Ch[(size_t)r * 256 + bc + ct * 16] = (_Float16)(acc[ct][j] * sc);
                    } else {
#pragma unroll
                        for (int ct = 0; ct < 4; ++ct)
                            Ch[(size_t)r * 256 + bc + ct * 16] =
                                (_Float16)fmaxf(acc[ct][j] + bb[ct], 0.f);
                    }
                }
            }
        }
        __syncthreads();   // protect As before next stage
    }
}

// ---------------- pooled mean + linear head ----------------

__global__ __launch_bounds__(256) void k_pool_head(
    const float* __restrict__ h2, const int* __restrict__ gstart,
    const float* __restrict__ Wl, const float* __restrict__ bl,
    float* __restrict__ out, int G) {
    int g = blockIdx.x;
    int t = threadIdx.x;
    int i0 = gstart[g], i1 = gstart[g + 1];
    float s = 0.f;
    for (int i = i0; i < i1; ++i) s += h2[(size_t)i * 256 + t];
    float cnt = (float)(i1 - i0);
    float pooled = s / fmaxf(cnt, 1.f);
    float v = pooled * Wl[t];
#pragma unroll
    for (int off = 32; off > 0; off >>= 1) v += __shfl_down(v, off, 64);
    __shared__ float red[4];
    if ((t & 63) == 0) red[t >> 6] = v;
    __syncthreads();
    if (t == 0) out[g] = red[0] + red[1] + red[2] + red[3] + bl[0];
}

// ---------------- launch ----------------

extern "C" void kernel_launch(void* const* d_in, const int* in_sizes, int n_in,
                              void* d_out, int out_size, void* d_ws, size_t ws_size,
                              hipStream_t stream) {
    const float* x  = (const float*)d_in[0];
    const int* ei   = (const int*)d_in[1];
    const int* batch= (const int*)d_in[2];
    const float* W1 = (const float*)d_in[3];
    const float* b1 = (const float*)d_in[4];
    const float* W2 = (const float*)d_in[5];
    const float* b2 = (const float*)d_in[6];
    const float* Wl = (const float*)d_in[7];
    const float* bl = (const float*)d_in[8];
    float* out = (float*)d_out;

    const int N = in_sizes[2];
    const int E = in_sizes[1] / 2;
    const int G = out_size;

    // Workspace: identical footprint to R4's passing layout (+192 KB weights).
    // All fp16 intermediates alias dead regions of the two big f32 buffers.
    char* wsp = (char*)d_ws;
    size_t off = 0;
    auto carve = [&](size_t bytes) -> void* {
        void* p = wsp + off;
        off = (off + bytes + 255) & ~(size_t)255;
        return p;
    };
    float* bufA    = (float*)carve((size_t)N * 256 * 4);
    float* bufB    = (float*)carve((size_t)N * 256 * 4);
    float* dinv    = (float*)carve((size_t)N * 4);
    int* ecnt      = (int*)carve((size_t)N * 4);
    int* rowstart  = (int*)carve((size_t)(N + 1) * 4);
    int* cursor    = (int*)carve((size_t)N * 4);
    int* ssrc      = (int*)carve((size_t)E * 4);
    const int NB = (N + 1023) / 1024;
    int* bsum      = (int*)carve((size_t)NB * 4);
    int* boff      = (int*)carve((size_t)NB * 4);
    int* gstart    = (int*)carve((size_t)(G + 1) * 4);
    _Float16* W1t  = (_Float16*)carve((size_t)256 * 128 * 2);
    _Float16* W2t  = (_Float16*)carve((size_t)256 * 256 * 2);
    (void)ws_size;

    // aliases (liveness-checked, sequential stream):
    __half*    xh   = (__half*)bufA;                              // [N*128 f16]
    __half*    xa_h = (__half*)((char*)bufA + (size_t)N * 128 * 2); // [N*128 f16]
    _Float16*  h1h  = (_Float16*)((char*)bufA + (size_t)N * 128 * 4); // [N*256 f16]
    _Float16*  hsh  = (_Float16*)bufB;                            // [N*256 f16]
    float*     h2   = bufA;                                       // [N*256 f32] after h1h dead

    const int* esrc = ei;
    const int* edst = ei + E;

    int nb256 = (N + 255) / 256;
    int eb256 = (E + 255) / 256;
    int nchunks = (N + 63) / 64;

    hipLaunchKernelGGL(k_init, dim3(nb256), dim3(256), 0, stream, ecnt, cursor, N);
    hipLaunchKernelGGL(k_edge_count, dim3(eb256), dim3(256), 0, stream, edst, ecnt, E);
    hipLaunchKernelGGL(k_scanA, dim3(NB), dim3(256), 0, stream, ecnt, bsum, N);
    hipLaunchKernelGGL(k_scanB, dim3(1), dim3(256), 0, stream, bsum, boff, NB);
    hipLaunchKernelGGL(k_scanC, dim3(NB), dim3(256), 0, stream, ecnt, boff, rowstart, dinv, N);
    hipLaunchKernelGGL(k_tail, dim3(1), dim3(1), 0, stream, rowstart, N, E);
    hipLaunchKernelGGL(k_scatter, dim3(eb256), dim3(256), 0, stream, esrc, edst, rowstart, cursor, ssrc, E);
    hipLaunchKernelGGL(k_gstarts, dim3(nb256), dim3(256), 0, stream, batch, gstart, N, G);
    hipLaunchKernelGGL(k_cast_f2h, dim3((N * 32 + 255) / 256), dim3(256), 0, stream,
                       x, xh, N * 32);
    hipLaunchKernelGGL(k_wt, dim3(128), dim3(256), 0, stream, W1, W1t, 128);
    hipLaunchKernelGGL(k_wt, dim3(256), dim3(256), 0, stream, W2, W2t, 256);

    // layer 1: xa_h = (half) Ahat x ; h1h = (half) relu(xa_h @ W1 + b1)
    hipLaunchKernelGGL(k_agg_in, dim3((N + 7) / 8), dim3(256), 0, stream,
                       x, xh, rowstart, ssrc, dinv, xa_h, N);
    hipLaunchKernelGGL((k_gemm_mfma<128, 1>), dim3(512), dim3(256), 0, stream,
                       (const _Float16*)xa_h, W1t, (const float*)nullptr, b1, h1h, N, nchunks);
    // layer 2: hsh = (half)(dinv * (h1h @ W2)); h2 = relu(dinv*(agg hsh) + b2)
    hipLaunchKernelGGL((k_gemm_mfma<256, 0>), dim3(512), dim3(256), 0, stream,
                       h1h, W2t, dinv, (const float*)nullptr, hsh, N, nchunks);
    hipLaunchKernelGGL(k_aggregate, dim3((N + 3) / 4), dim3(256), 0, stream,
                       (const __half*)hsh, rowstart, ssrc, dinv, b2, h2, N);
    // pool + head
    hipLaunchKernelGGL(k_pool_head, dim3(G), dim3(256), 0, stream, h2, gstart, Wl, bl, out, G);
}